// Round 5
// baseline (43.023 us; speedup 1.0000x reference)
//
#include <hip/hip_runtime.h>
#include <stdint.h>

#define NA   3
#define KCH  8       // 5 + NUM_CLASSES
#define BLKA 512
#define BLKB 1024
#define QCAP 1024

#define LOG2E 1.4426950408889634f
#define LN2   0.6931471805599453f

struct ScaleParams {
  const float*   pred;    // (B, 24, H, W)
  const float*   boxes;   // (B, N, 4)
  const int*     labels;  // (B, N)
  const uint8_t* pos;     // (B, N) bool
  const uint8_t* neg;     // (B, N) bool
  int HW;
};

__device__ __forceinline__ float fexp2(float x) { return __builtin_amdgcn_exp2f(x); }
__device__ __forceinline__ float flog2(float x) { return __builtin_amdgcn_logf(x); }

// logaddexp(0,x) = max(x,0) + log1p(exp(-|x|)), native exp2/log2 (~1e-6 rel)
__device__ __forceinline__ float softplus_fast(float x) {
  const float t = fexp2(-fabsf(x) * LOG2E);
  return fmaxf(x, 0.f) + flog2(1.f + t) * LN2;
}

__device__ __forceinline__ float sl1f(float d) {
  float ad = fabsf(d);
  return (ad < 1.f) ? 0.5f * d * d : ad - 0.5f;
}

// order-preserving float->uint key (larger float => larger key)
__device__ __forceinline__ unsigned fkey(unsigned u) {
  return (u & 0x80000000u) ? ~u : (u | 0x80000000u);
}
__device__ __forceinline__ unsigned funkey(unsigned k) {
  return (k & 0x80000000u) ? (k & 0x7FFFFFFFu) : ~k;
}

template<int NTHR>
__device__ __forceinline__ float blockSum(float v, float* scr) {
  #pragma unroll
  for (int off = 32; off > 0; off >>= 1) v += __shfl_down(v, off);
  const int lane = threadIdx.x & 63, w = threadIdx.x >> 6;
  __syncthreads();                       // protect scr reuse
  if (lane == 0) scr[w] = v;
  __syncthreads();
  float r = 0.f;
  #pragma unroll
  for (int i = 0; i < NTHR / 64; ++i) r += scr[i];  // same-address broadcast
  return r;
}

// Per-thread Q consecutive bins (count, value-sum) of an ascending-key hist:
// find bin holding the krem-th LARGEST, remaining count in it, and value-sum
// of all strictly-higher bins (+ sa_in). Block-uniform; results in sh_*.
template<int NTHR, int Q>
__device__ __forceinline__ void selectDigit(const unsigned* cb, const float* sb,
    int krem_in, float sa_in, int* iwav, float* fwav,
    int* sh_dig, int* sh_krem, float* sh_sa) {
  const int t = threadIdx.x, lane = t & 63, w = t >> 6;
  int c_t = 0; float s_t = 0.f;
  #pragma unroll
  for (int q = 0; q < Q; ++q) { c_t += (int)cb[q]; s_t += sb[q]; }
  int ci = c_t; float si = s_t;          // wave inclusive suffix scan
  #pragma unroll
  for (int off = 1; off < 64; off <<= 1) {
    const int   co = __shfl_down(ci, off);
    const float so = __shfl_down(si, off);
    if (lane + off < 64) { ci += co; si += so; }
  }
  __syncthreads();                       // protect iwav/fwav reuse
  if (lane == 0) { iwav[w] = ci; fwav[w] = si; }
  __syncthreads();
  int ac = 0; float as = 0.f;
  for (int w2 = w + 1; w2 < NTHR / 64; ++w2) { ac += iwav[w2]; as += fwav[w2]; }
  int   cum_c = (ci - c_t) + ac;         // strictly above this thread's top bin
  float cum_s = (si - s_t) + as;
  #pragma unroll
  for (int q = Q - 1; q >= 0; --q) {
    const int cq = (int)cb[q];
    if (cq > 0 && cum_c < krem_in && krem_in <= cum_c + cq) {  // unique
      *sh_dig  = t * Q + q;
      *sh_krem = krem_in - cum_c;
      *sh_sa   = sa_in + cum_s;
    }
    cum_c += cq; cum_s += sb[q];
  }
  __syncthreads();
}

// Top-k softplus-sum over negatives of one row. h1 = stage-1 counts (2048
// bins of key>>21; LDS or global). Sweeps the row once: softplus only for
// elements at/above the stage-1 bin. Requires k > 0, block-uniform.
template<int NTHR>
__device__ float topk_sum(int k, const unsigned* h1, const float* predb,
    const uint8_t* negrow, int HW,
    unsigned* hc, float* hs, int* iwav, float* fwav, float* fscr,
    int* sh_dig, int* sh_krem, float* sh_sa) {
  constexpr int Q = 2048 / NTHR;
  const int t = threadIdx.x;
  const int N = NA * HW;

  unsigned cb[Q]; float sb[Q];
  #pragma unroll
  for (int q = 0; q < Q; ++q) { cb[q] = h1[Q * t + q]; sb[q] = 0.f; }
  selectDigit<NTHR, Q>(cb, sb, k, 0.f, iwav, fwav, sh_dig, sh_krem, sh_sa);
  const int bin1 = *sh_dig; const int krem1 = *sh_krem;

  for (int i = t; i < 2048; i += NTHR) { hc[i] = 0u; hs[i] = 0.f; }
  __syncthreads();

  float sgt = 0.f;
  for (int c4 = t * 4; c4 < N; c4 += NTHR * 4) {
    const int a = (c4 >= HW) + (c4 >= 2 * HW);
    const int cell = c4 - a * HW;
    const float4 o4 = *(const float4*)(predb + (size_t)a * KCH * HW + 4 * HW + cell);
    const uchar4 nm = *(const uchar4*)(negrow + c4);
    #pragma unroll
    for (int q = 0; q < 4; ++q) {
      if ((&nm.x)[q]) {
        const float obj = (&o4.x)[q];
        const unsigned key = fkey(__float_as_uint(obj));
        const int kb = (int)(key >> 21);
        if (kb > bin1) sgt += softplus_fast(obj);
        else if (kb == bin1) {
          const float sp = softplus_fast(obj);
          atomicAdd(&hc[(key >> 10) & 2047], 1u);
          atomicAdd(&hs[(key >> 10) & 2047], sp);
        }
      }
    }
  }
  __syncthreads();
  const float t_sgt = blockSum<NTHR>(sgt, fscr);
  #pragma unroll
  for (int q = 0; q < Q; ++q) { cb[q] = hc[Q * t + q]; sb[q] = hs[Q * t + q]; }
  selectDigit<NTHR, Q>(cb, sb, krem1, t_sgt, iwav, fwav, sh_dig, sh_krem, sh_sa);

  // tie bin edge approx: key bits[31:10] kept (13 mantissa bits) -> error
  // <= krem2 * |obj| * 2^-13 * dsp/dx <= ~2e-3, far below threshold.
  const unsigned Tkey = (((unsigned)bin1 << 11) | (unsigned)*sh_dig) << 10;
  const float Tsp = softplus_fast(__uint_as_float(funkey(Tkey)));
  return *sh_sa + (float)*sh_krem * Tsp;
}

__device__ __forceinline__ void emit_row(int npos, float posobj, float sel,
    float ce, float loc, float* out, unsigned* done, int arrivals, float invB) {
  if (threadIdx.x == 0) {
    const float denom = (float)max(npos, 1);
    atomicAdd(&out[1], (posobj + sel) / denom);
    if (npos > 0) {
      atomicAdd(&out[2], ce / denom);
      atomicAdd(&out[3], loc / (denom * 4.f));
    }
    __threadfence();
    const unsigned old = atomicAdd(done, 1u);
    if (old == (unsigned)(arrivals - 1)) {     // last arrival finalizes
      const float o = atomicAdd(&out[1], 0.f) * invB;
      const float c = atomicAdd(&out[2], 0.f) * invB;
      const float l = atomicAdd(&out[3], 0.f) * invB;
      out[0] = o + c + l;
      out[1] = o;
      out[2] = c;
      out[3] = l;
    }
  }
}

__global__ void k_zero(float4* ws4, int nw4, float* out) {
  const float4 z = {0.f, 0.f, 0.f, 0.f};
  for (int i = blockIdx.x * blockDim.x + threadIdx.x; i < nw4;
       i += gridDim.x * blockDim.x) ws4[i] = z;
  if (blockIdx.x == 0 && threadIdx.x < 4) out[threadIdx.x] = 0.f;
}

// Scan kernel. mono=0: bid<4B -> scale-0 slice (hist+scalars to global);
// [4B,5B) -> scale-1 whole row; [5B,6B) -> scale-2 whole row (local select).
// mono=1: grid=R, every block owns a whole row (fallback, no workspace).
__global__ __launch_bounds__(BLKA) void k_scan(
    ScaleParams p0, ScaleParams p1, ScaleParams p2,
    int B, int R, float invB,
    unsigned* g_cnt, float* g_scal, unsigned* done, float* out, int mono) {
  __shared__ unsigned hc[2048];
  __shared__ float    hs[2048];
  __shared__ int      queue[QCAP];
  __shared__ int      sh_qn;
  __shared__ int      iwav[BLKA / 64];
  __shared__ float    fwav[BLKA / 64];
  __shared__ float    fscr[BLKA / 64];
  __shared__ int      sh_dig, sh_krem;
  __shared__ float    sh_sa;

  const int bid = blockIdx.x;
  int s, b, c0, c1;
  bool whole;
  if (mono) {
    const int r0 = bid; s = r0 / B; b = r0 % B;
    c0 = 0; c1 = 0; whole = true;            // c1 set below from HW
  } else if (bid < 4 * B) {
    s = 0; b = bid >> 2; const int sl = bid & 3;
    c0 = sl * 4800; c1 = c0 + 4800; whole = false;
  } else if (bid < 5 * B) {
    s = 1; b = bid - 4 * B; c0 = 0; c1 = 4800; whole = true;
  } else {
    s = 2; b = bid - 5 * B; c0 = 0; c1 = 1200; whole = true;
  }
  const ScaleParams P = (s == 0) ? p0 : (s == 1) ? p1 : p2;
  const int HW = P.HW, N = NA * HW;
  if (mono) c1 = N;
  const int r = s * B + b;
  const int t = threadIdx.x;

  for (int i = t; i < 2048; i += BLKA) hc[i] = 0u;
  if (t == 0) sh_qn = 0;
  __syncthreads();

  const float* predb = P.pred + (size_t)b * (NA * KCH) * HW;
  const size_t row = (size_t)b * N;
  float nneg = 0.f;

  // ---- sweep: raw-key histogram (no transcendentals) + pos queue ----
  for (int c4 = c0 + t * 4; c4 < c1; c4 += BLKA * 4) {
    const int a = (c4 >= HW) + (c4 >= 2 * HW);
    const int cell = c4 - a * HW;
    const float4 o4 = *(const float4*)(predb + (size_t)a * KCH * HW + 4 * HW + cell);
    const uchar4 pm = *(const uchar4*)(P.pos + row + c4);
    const uchar4 nm = *(const uchar4*)(P.neg + row + c4);
    #pragma unroll
    for (int q = 0; q < 4; ++q) {
      if ((&nm.x)[q]) {
        nneg += 1.f;
        atomicAdd(&hc[fkey(__float_as_uint((&o4.x)[q])) >> 21], 1u);
      }
      if ((&pm.x)[q]) {
        const int idx = atomicAdd(&sh_qn, 1);
        if (idx < QCAP) queue[idx] = c4 + q;
      }
    }
  }
  __syncthreads();
  const int npos = sh_qn;
  const int qn = min(npos, QCAP);

  // ---- dense pos-anchor work (softplus/CE/smooth-L1 only here, ~1%) ----
  float posobj = 0.f, ce = 0.f, loc = 0.f;
  for (int i = t; i < qn; i += BLKA) {
    const int j = queue[i];
    const int a = (j >= HW) + (j >= 2 * HW);
    const int cell = j - a * HW;
    const float* pa = predb + (size_t)a * KCH * HW;
    posobj += softplus_fast(-pa[4 * HW + cell]);   // sp(x)-x == sp(-x)
    const float c0f = pa[5 * HW + cell];
    const float c1f = pa[6 * HW + cell];
    const float c2f = pa[7 * HW + cell];
    const float m = fmaxf(fmaxf(c0f, c1f), c2f);
    const float e = fexp2((c0f - m) * LOG2E) + fexp2((c1f - m) * LOG2E)
                  + fexp2((c2f - m) * LOG2E);
    const float lse = m + flog2(e) * LN2;
    const int lab = P.labels[row + j];
    ce += lse - ((lab == 0) ? c0f : (lab == 1) ? c1f : c2f);
    const float4 bx = *(const float4*)(P.boxes + (size_t)(row + j) * 4);
    loc += sl1f(pa[0 * HW + cell] - bx.x) + sl1f(pa[1 * HW + cell] - bx.y)
         + sl1f(pa[2 * HW + cell] - bx.z) + sl1f(pa[3 * HW + cell] - bx.w);
  }

  const float t_nneg   = blockSum<BLKA>(nneg, fscr);
  const float t_posobj = blockSum<BLKA>(posobj, fscr);
  const float t_ce     = blockSum<BLKA>(ce, fscr);
  const float t_loc    = blockSum<BLKA>(loc, fscr);

  if (!whole) {
    // contribute slice results to the row's global state
    if (t == 0) {
      atomicAdd(&g_scal[r * 8 + 0], (float)npos);
      atomicAdd(&g_scal[r * 8 + 1], t_nneg);
      atomicAdd(&g_scal[r * 8 + 2], t_posobj);
      atomicAdd(&g_scal[r * 8 + 3], t_ce);
      atomicAdd(&g_scal[r * 8 + 4], t_loc);
    }
    for (int i = t; i < 2048; i += BLKA) {
      const unsigned c = hc[i];
      if (c) atomicAdd(&g_cnt[(size_t)r * 2048 + i], c);
    }
  } else {
    const int k = min(3 * npos, (int)t_nneg);
    float sel = 0.f;
    if (k > 0)
      sel = topk_sum<BLKA>(k, hc, predb, P.neg + row, HW,
                           hc, hs, iwav, fwav, fscr, &sh_dig, &sh_krem, &sh_sa);
    emit_row(npos, t_posobj, sel, t_ce, t_loc, out, done, R, invB);
  }
}

// Select kernel: one block per scale-0 row; stage-1 from global hist.
__global__ __launch_bounds__(BLKB) void k_select(
    ScaleParams p0, int B, int R, float invB,
    const unsigned* g_cnt, const float* g_scal, unsigned* done, float* out) {
  __shared__ unsigned hc[2048];
  __shared__ float    hs[2048];
  __shared__ int      iwav[BLKB / 64];
  __shared__ float    fwav[BLKB / 64];
  __shared__ float    fscr[BLKB / 64];
  __shared__ int      sh_dig, sh_krem;
  __shared__ float    sh_sa;

  const int r = blockIdx.x;               // scale-0 rows: global row id == r
  const int HW = p0.HW, N = NA * HW;
  const float* predb = p0.pred + (size_t)r * (NA * KCH) * HW;
  const size_t row = (size_t)r * N;

  const int   npos   = (int)g_scal[r * 8 + 0];
  const int   nneg   = (int)g_scal[r * 8 + 1];
  const float posobj = g_scal[r * 8 + 2];
  const float ce     = g_scal[r * 8 + 3];
  const float loc    = g_scal[r * 8 + 4];
  const int k = min(3 * npos, nneg);

  float sel = 0.f;
  if (k > 0)
    sel = topk_sum<BLKB>(k, g_cnt + (size_t)r * 2048, predb, p0.neg + row, HW,
                         hc, hs, iwav, fwav, fscr, &sh_dig, &sh_krem, &sh_sa);
  emit_row(npos, posobj, sel, ce, loc, out, done, R, invB);
}

extern "C" void kernel_launch(void* const* d_in, const int* in_sizes, int n_in,
                              void* d_out, int out_size, void* d_ws, size_t ws_size,
                              hipStream_t stream) {
  (void)n_in; (void)out_size;

  const int HW0 = 80 * 80, HW1 = 40 * 40, HW2 = 20 * 20;
  const int B = in_sizes[0] / (NA * KCH * HW0);
  const int R = 3 * B;
  const float invB = 1.f / (float)B;

  ScaleParams p0{(const float*)d_in[0],  (const float*)d_in[1],
                 (const int*)d_in[2],    (const uint8_t*)d_in[3],
                 (const uint8_t*)d_in[4], HW0};
  ScaleParams p1{(const float*)d_in[5],  (const float*)d_in[6],
                 (const int*)d_in[7],    (const uint8_t*)d_in[8],
                 (const uint8_t*)d_in[9], HW1};
  ScaleParams p2{(const float*)d_in[10], (const float*)d_in[11],
                 (const int*)d_in[12],   (const uint8_t*)d_in[13],
                 (const uint8_t*)d_in[14], HW2};

  float* out = (float*)d_out;

  const size_t cntBytes  = (size_t)R * 2048 * 4;
  const size_t scalBytes = (size_t)R * 32;
  const size_t need = cntBytes + scalBytes + 16;

  if (ws_size >= need) {
    unsigned* g_cnt  = (unsigned*)d_ws;
    float*    g_scal = (float*)((char*)d_ws + cntBytes);
    unsigned* done   = (unsigned*)((char*)d_ws + cntBytes + scalBytes);
    const int nw4 = (int)((need + 15) / 16);
    int zgrid = (nw4 + 255) / 256; if (zgrid > 2048) zgrid = 2048;
    k_zero<<<zgrid, 256, 0, stream>>>((float4*)d_ws, nw4, out);
    k_scan<<<6 * B, BLKA, 0, stream>>>(p0, p1, p2, B, R, invB,
                                       g_cnt, g_scal, done, out, 0);
    k_select<<<B, BLKB, 0, stream>>>(p0, B, R, invB, g_cnt, g_scal, done, out);
  } else {
    // fallback: whole-row blocks, no global histograms (only 'done' in ws)
    unsigned* done = (unsigned*)d_ws;
    k_zero<<<1, 256, 0, stream>>>((float4*)d_ws, 1, out);
    k_scan<<<R, BLKA, 0, stream>>>(p0, p1, p2, B, R, invB,
                                   (unsigned*)d_ws, (float*)d_ws, done, out, 1);
  }
}